// Round 12
// baseline (257.071 us; speedup 1.0000x reference)
//
#include <hip/hip_runtime.h>
#include <hip/hip_bf16.h>

#define NN 4096      // total nodes
#define NPER 1024    // nodes per graph
#define DD 128       // feat dim
#define BB 4         // graphs
#define KK 512       // kept per graph
#define EE 65536     // total directed edges
#define NBLK 256     // mega grid (256 x 256 = 1024 waves, all co-resident)
#define FSTRIDE 16   // flag padding: 64B per block -> no line sharing

// spectral_loss == 0 analytically: 4 disconnected components before AND
// after pooling -> normalized-Laplacian Fiedler value 0 both times.
//
// Round-9 lesson: single-counter spin barrier = serialized RMWs ~17us/bar.
// This round: flag-ARRAY barrier (store own flag, load-poll distinct flags)
// -> no RMW contention. 2 dispatches total; all phases spread on 256 blocks.

// ---------------- K1: h = x@W + zero deg/acc/flags + loss ------------------
__global__ void k1_init_h(const float* __restrict__ x, const float* __restrict__ W,
                          float* __restrict__ h, int* __restrict__ deg,
                          float* __restrict__ acc, int* __restrict__ flags,
                          float* __restrict__ out, int out_size) {
    const int t = threadIdx.x, b = blockIdx.x;
    const int gt = b * 256 + t;
    if (gt < NN) { deg[gt] = 0; acc[gt] = 0.0f; }
    if (gt < NBLK * FSTRIDE) flags[gt] = 0;    // barrier flags
    if (gt == 0) out[out_size - 1] = 0.0f;     // spectral_loss

    const int lane = t & 63, w = t >> 6;       // 4 waves/block
    const float2 w2 = ((const float2*)W)[lane];
    int rbase = b * 16 + w * 4;                // 4 rows per wave
    float v[4];
    #pragma unroll
    for (int k = 0; k < 4; ++k) {
        const float2 xv = ((const float2*)(x + (size_t)(rbase + k) * DD))[lane];
        v[k] = xv.x * w2.x + xv.y * w2.y;
    }
    #pragma unroll
    for (int k = 0; k < 4; ++k) {
        float s = v[k];
        for (int off = 32; off; off >>= 1) s += __shfl_down(s, off);
        if (lane == 0) h[rbase + k] = s;
    }
}

// ---------------- flag-array device barrier --------------------------------
// Block b release-stores flags[b]; thread t acquire-polls flags[t] (1:1,
// 256 threads x 256 blocks). Pure loads -> no RMW serialization. The t<->b
// pairing gives exactly the release/acquire edge needed for counts[t] in D2.
__device__ __forceinline__ void fastbar(int* flags, int phase) {
    __syncthreads();                           // block's phase work done
    if (threadIdx.x == 0) {
        __threadfence();                       // release phase writes
        __hip_atomic_store(flags + blockIdx.x * FSTRIDE, phase,
                           __ATOMIC_RELEASE, __HIP_MEMORY_SCOPE_AGENT);
    }
    int* myf = flags + threadIdx.x * FSTRIDE;
    while (__hip_atomic_load(myf, __ATOMIC_ACQUIRE,
                             __HIP_MEMORY_SCOPE_AGENT) < phase)
        __builtin_amdgcn_s_sleep(4);
    __syncthreads();
    __threadfence();                           // belt-and-braces acquire
}

// ---------------- MEGA: deg | scatter | rank+x_new | resolve | write -------
__global__ void __launch_bounds__(256)
mega(const float* __restrict__ x, const int* __restrict__ ei,
     const float* __restrict__ h, const float* __restrict__ bp,
     int* __restrict__ deg, float* __restrict__ acc,
     int* __restrict__ lnewid, unsigned* __restrict__ packed,
     int* __restrict__ counts, int* __restrict__ flags,
     float* __restrict__ out, int esel, int off_e, int off_b) {
    const int t = threadIdx.x, b = blockIdx.x;
    const int gt = b * 256 + t;
    const int lane = t & 63, wid = t >> 6;
    __shared__ __align__(16) unsigned int keys[NPER];
    __shared__ float sco[NPER];
    __shared__ int wsum[4], wred[4], wbase[4];

    // ---- phase A: in-degree atomics (deg zeroed by K1) ----
    atomicAdd(&deg[ei[EE + gt]], 1);
    fastbar(flags, 1);

    // ---- phase B: edge scatter ----
    {
        int s = ei[gt], c = ei[EE + gt];
        float rs = rsqrtf((float)(deg[s] + 1));     // +1 = self loop
        float rc = rsqrtf((float)(deg[c] + 1));
        atomicAdd(&acc[c], rs * rc * h[s]);
    }
    fastbar(flags, 2);

    // ---- phase C: rank-by-count top-K + batch_new + x_new ----
    // 64 blocks/graph; block ranks 16 nodes; 16 threads cooperate per node.
    // rank = #(key > mine) + #(key == mine && idx < mine) == lax.top_k order.
    {
        const int g = b >> 6;                  // graph
        const int chunk = b & 63;              // 16-node chunk
        const float bb = bp[0];
        #pragma unroll
        for (int k = 0; k < 4; ++k) {
            int ln = t + k * 256;
            int an = g * NPER + ln;
            float sc = tanhf(acc[an] + h[an] / (float)(deg[an] + 1) + bb);
            sco[ln] = sc;
            unsigned int bits = __float_as_uint(sc);
            keys[ln] = (bits & 0x80000000u) ? ~bits : (bits | 0x80000000u);
        }
        __syncthreads();
        const int ni = t >> 4;                 // node within chunk (0..15)
        const int j  = t & 15;                 // key slice / row lane (0..15)
        const int ln = chunk * 16 + ni;        // graph-local node id
        const int an = g * NPER + ln;
        const unsigned int kt = keys[ln];
        int cnt = 0;
        const uint4* kv = (const uint4*)keys;
        #pragma unroll
        for (int i = 0; i < 16; ++i) {
            int c = (i + j) & 15;              // swizzle -> 2-way conflicts (free)
            uint4 q = kv[j * 16 + c];
            int bi = j * 64 + c * 4;
            cnt += (q.x > kt) + (q.y > kt) + (q.z > kt) + (q.w > kt);
            cnt += (q.x == kt && (bi + 0) < ln);
            cnt += (q.y == kt && (bi + 1) < ln);
            cnt += (q.z == kt && (bi + 2) < ln);
            cnt += (q.w == kt && (bi + 3) < ln);
        }
        cnt += __shfl_xor(cnt, 1, 16);
        cnt += __shfl_xor(cnt, 2, 16);
        cnt += __shfl_xor(cnt, 4, 16);
        cnt += __shfl_xor(cnt, 8, 16);         // full rank in all 16 lanes
        const int kept = (cnt < KK);
        const int nid = kept ? (g * KK + cnt) : -1;  // GLOBAL new id
        if (j == 0) {
            lnewid[an] = nid;
            if (kept) out[off_b + nid] = (float)g;   // batch_new
        }
        if (kept) {
            // 16 lanes write this node's 512B x_new row: 2 float4 each
            float sc = sco[ln];
            const float4* xr = (const float4*)x + (size_t)an * 32;
            float4* orow = (float4*)out + (size_t)nid * 32;
            float4 a = xr[j * 2], b2 = xr[j * 2 + 1];
            a.x *= sc; a.y *= sc; a.z *= sc; a.w *= sc;
            b2.x *= sc; b2.y *= sc; b2.z *= sc; b2.w *= sc;
            orow[j * 2] = a;
            orow[j * 2 + 1] = b2;
        }
    }
    fastbar(flags, 3);

    // ---- phase D1: edge resolve -> packed + per-block counts ----
    {
        int rn = lnewid[ei[gt]];
        int cn = lnewid[ei[EE + gt]];
        int f = (rn >= 0) & (cn >= 0);
        packed[gt] = f ? (((unsigned)rn << 16) | (unsigned)cn) : 0xFFFFFFFFu;
        unsigned long long mask = __ballot(f);
        if (lane == 0) wsum[wid] = (int)__popcll(mask);
        __syncthreads();
        if (t == 0) counts[b] = wsum[0] + wsum[1] + wsum[2] + wsum[3];
    }
    fastbar(flags, 4);

    // ---- phase D2: parallel cross-block prefix + stable ordered write ----
    {
        unsigned pv = packed[gt];              // own block's writes
        int f = (pv != 0xFFFFFFFFu);
        unsigned long long mask = __ballot(f);
        int wpos = (int)__popcll(mask & ((1ull << lane) - 1ull));
        if (lane == 0) wsum[wid] = (int)__popcll(mask);
        // counts[t]: thread t acquired block t's flag -> visibility paired
        int c = (t < b) ? counts[t] : 0;
        for (int off = 32; off; off >>= 1) c += __shfl_down(c, off);
        if (lane == 0) wred[wid] = c;
        __syncthreads();
        if (t == 0) {
            int base = wred[0] + wred[1] + wred[2] + wred[3];
            #pragma unroll
            for (int k = 0; k < 4; ++k) { wbase[k] = base; base += wsum[k]; }
        }
        __syncthreads();
        if (f) {
            int pos = wbase[wid] + wpos;
            if (pos < esel) {
                out[off_e + pos]        = (float)(pv >> 16);
                out[off_e + esel + pos] = (float)(pv & 0xffffu);
            }
        }
    }
}

// ================================================================ launch
extern "C" void kernel_launch(void* const* d_in, const int* in_sizes, int n_in,
                              void* d_out, int out_size, void* d_ws, size_t ws_size,
                              hipStream_t stream) {
    const float* x  = (const float*)d_in[0];
    const int*   ei = (const int*)d_in[1];
    // d_in[2] = batch (derived analytically, unused)
    const float* W  = (const float*)d_in[3];
    const float* bp = (const float*)d_in[4];
    float* out = (float*)d_out;

    int esel  = (out_size - BB * KK * DD - BB * KK - 1) / 2;  // kept-edge count
    int off_e = BB * KK * DD;
    int off_b = off_e + 2 * esel;

    float*    ws     = (float*)d_ws;
    float*    h      = ws;                        // NN floats
    float*    acc    = ws + NN;                   // NN floats
    int*      deg    = (int*)(ws + 2 * NN);       // NN ints
    int*      lnewid = deg + NN;                  // NN ints
    unsigned* packed = (unsigned*)(lnewid + NN);  // EE uints
    int*      counts = (int*)(packed + EE);       // NBLK ints
    int*      flags  = counts + NBLK;             // NBLK*FSTRIDE ints

    k1_init_h<<<256, 256, 0, stream>>>(x, W, h, deg, acc, flags, out, out_size);
    mega<<<NBLK, 256, 0, stream>>>(x, ei, h, bp, deg, acc, lnewid, packed,
                                   counts, flags, out, esel, off_e, off_b);
}

// Round 13
// 84.655 us; speedup vs baseline: 3.0367x; 3.0367x over previous
//
#include <hip/hip_runtime.h>
#include <hip/hip_bf16.h>

#define NN 4096      // total nodes
#define NPER 1024    // nodes per graph
#define DD 128       // feat dim
#define BB 4         // graphs
#define KK 512       // kept per graph
#define EE 65536     // total directed edges

// spectral_loss == 0 analytically: 4 disconnected components before AND
// after pooling -> normalized-Laplacian Fiedler value 0 both times.
//
// Final structure (round-8 validated, 83.9us): 6 fully-spread dispatches.
// Measured on MI355X: dispatch gap ~4.5us < single-counter spin barrier
// ~17us/bar (r9) < flag-array barrier ~45us/bar (r12) < coop grid.sync
// ~9us/sync + ~35us launch overhead (r2/r4). Phase concentration on few
// CUs loses ~20us (r4/r10). Hence: chain of small spread kernels.
// Floor decomposition: 40.4us harness ws-poison fill + ~2us restores
// + ~12us work + ~27us launch gaps.

// ---------------- K1: zero deg/acc, h = x@W (wave-per-row), loss=0 ----------
__global__ void k1_init_h(const float* __restrict__ x, const float* __restrict__ W,
                          float* __restrict__ h, int* __restrict__ deg,
                          float* __restrict__ acc, float* __restrict__ out,
                          int out_size) {
    const int t = threadIdx.x, b = blockIdx.x;
    const int gt = b * 256 + t;
    if (gt < NN) { deg[gt] = 0; acc[gt] = 0.0f; }
    if (gt == 0) out[out_size - 1] = 0.0f;     // spectral_loss

    const int lane = t & 63, w = t >> 6;       // 4 waves/block
    const float2 w2 = ((const float2*)W)[lane];
    int rbase = b * 16 + w * 4;                // 4 rows per wave
    float v[4];
    #pragma unroll
    for (int k = 0; k < 4; ++k) {
        const float2 xv = ((const float2*)(x + (size_t)(rbase + k) * DD))[lane];
        v[k] = xv.x * w2.x + xv.y * w2.y;
    }
    #pragma unroll
    for (int k = 0; k < 4; ++k) {
        float s = v[k];
        for (int off = 32; off; off >>= 1) s += __shfl_down(s, off);
        if (lane == 0) h[rbase + k] = s;
    }
}

// ---------------- K2: in-degree atomics ------------------------------------
__global__ void k2_deg(const int* __restrict__ ei, int* __restrict__ deg) {
    int gt = blockIdx.x * 256 + threadIdx.x;
    atomicAdd(&deg[ei[EE + gt]], 1);
}

// ---------------- K3: edge scatter -----------------------------------------
__global__ void k3_scatter(const int* __restrict__ ei, const int* __restrict__ deg,
                           const float* __restrict__ h, float* __restrict__ acc) {
    int gt = blockIdx.x * 256 + threadIdx.x;
    int s = ei[gt], c = ei[EE + gt];
    float rs = rsqrtf((float)(deg[s] + 1));    // +1 = self loop
    float rc = rsqrtf((float)(deg[c] + 1));
    atomicAdd(&acc[c], rs * rc * h[s]);
}

// ---------------- K4: rank-by-count top-K + batch_new + x_new --------------
// 64 blocks/graph; block ranks 16 nodes; 16 threads cooperate per node.
// rank = #(key > mine) + #(key == mine && idx < mine)  == lax.top_k order.
// Kept nodes' x_new rows are written right here (rank + score known).
__global__ void k4_rank(const float* __restrict__ x, const int* __restrict__ deg,
                        const float* __restrict__ h, const float* __restrict__ acc,
                        const float* __restrict__ bp, int* __restrict__ lnewid,
                        float* __restrict__ out, int off_b) {
    const int t = threadIdx.x;
    const int g = blockIdx.x >> 6;             // graph
    const int chunk = blockIdx.x & 63;         // 16-node chunk
    __shared__ __align__(16) unsigned int keys[NPER];
    __shared__ float sco[NPER];
    const float bb = bp[0];
    #pragma unroll
    for (int k = 0; k < 4; ++k) {
        int ln = t + k * 256;
        int an = g * NPER + ln;
        float sc = tanhf(acc[an] + h[an] / (float)(deg[an] + 1) + bb);
        sco[ln] = sc;
        unsigned int bits = __float_as_uint(sc);
        keys[ln] = (bits & 0x80000000u) ? ~bits : (bits | 0x80000000u);
    }
    __syncthreads();
    const int ni = t >> 4;                     // node within chunk (0..15)
    const int j  = t & 15;                     // key slice / row lane (0..15)
    const int ln = chunk * 16 + ni;            // graph-local node id
    const int an = g * NPER + ln;
    const unsigned int kt = keys[ln];
    int cnt = 0;
    const uint4* kv = (const uint4*)keys;
    #pragma unroll
    for (int i = 0; i < 16; ++i) {
        int c = (i + j) & 15;                  // swizzle -> 2-way conflicts (free)
        uint4 q = kv[j * 16 + c];
        int bi = j * 64 + c * 4;
        cnt += (q.x > kt) + (q.y > kt) + (q.z > kt) + (q.w > kt);
        cnt += (q.x == kt && (bi + 0) < ln);
        cnt += (q.y == kt && (bi + 1) < ln);
        cnt += (q.z == kt && (bi + 2) < ln);
        cnt += (q.w == kt && (bi + 3) < ln);
    }
    cnt += __shfl_xor(cnt, 1, 16);
    cnt += __shfl_xor(cnt, 2, 16);
    cnt += __shfl_xor(cnt, 4, 16);
    cnt += __shfl_xor(cnt, 8, 16);             // full rank in all 16 lanes
    const int kept = (cnt < KK);
    const int nid = kept ? (g * KK + cnt) : -1;     // GLOBAL new id
    if (j == 0) {
        lnewid[an] = nid;
        if (kept) out[off_b + nid] = (float)g;      // batch_new
    }
    if (kept) {
        // 16 lanes write this node's 512B x_new row: 2 float4 each
        float sc = sco[ln];
        const float4* xr = (const float4*)x + (size_t)an * 32;
        float4* orow = (float4*)out + (size_t)nid * 32;
        float4 a = xr[j * 2], b2 = xr[j * 2 + 1];
        a.x *= sc; a.y *= sc; a.z *= sc; a.w *= sc;
        b2.x *= sc; b2.y *= sc; b2.z *= sc; b2.w *= sc;
        orow[j * 2] = a;
        orow[j * 2 + 1] = b2;
    }
}

// ---------------- K5: edge resolve -> packed + per-block counts -------------
// 256 blocks x 256: block b owns 256 consecutive edges (order preserved).
__global__ void k5_resolve(const int* __restrict__ ei, const int* __restrict__ lnewid,
                           unsigned* __restrict__ packed, int* __restrict__ counts) {
    const int t = threadIdx.x, b = blockIdx.x;
    const int gt = b * 256 + t;
    __shared__ int wsum[4];
    int rn = lnewid[ei[gt]];
    int cn = lnewid[ei[EE + gt]];
    int f = (rn >= 0) & (cn >= 0);
    packed[gt] = f ? (((unsigned)rn << 16) | (unsigned)cn) : 0xFFFFFFFFu;
    unsigned long long mask = __ballot(f);
    if ((t & 63) == 0) wsum[t >> 6] = (int)__popcll(mask);
    __syncthreads();
    if (t == 0) counts[b] = wsum[0] + wsum[1] + wsum[2] + wsum[3];
}

// ---------------- K6: parallel cross-block prefix + stable ordered write ----
__global__ void k6_edges(const unsigned* __restrict__ packed,
                         const int* __restrict__ counts,
                         float* __restrict__ out, int esel, int off_e) {
    const int t = threadIdx.x, b = blockIdx.x;
    const int lane = t & 63, wid = t >> 6;
    __shared__ int wsum[4], wred[4], wbase[4];
    unsigned pv = packed[b * 256 + t];
    int f = (pv != 0xFFFFFFFFu);
    unsigned long long mask = __ballot(f);
    int wpos = (int)__popcll(mask & ((1ull << lane) - 1ull));
    if (lane == 0) wsum[wid] = (int)__popcll(mask);
    // parallel sum of counts[0..b-1]: thread t handles counts[t]
    int c = (t < b) ? counts[t] : 0;
    for (int off = 32; off; off >>= 1) c += __shfl_down(c, off);
    if (lane == 0) wred[wid] = c;
    __syncthreads();
    if (t == 0) {
        int base = wred[0] + wred[1] + wred[2] + wred[3];
        #pragma unroll
        for (int k = 0; k < 4; ++k) { wbase[k] = base; base += wsum[k]; }
    }
    __syncthreads();
    if (f) {
        int pos = wbase[wid] + wpos;
        if (pos < esel) {
            out[off_e + pos]        = (float)(pv >> 16);
            out[off_e + esel + pos] = (float)(pv & 0xffffu);
        }
    }
}

// ================================================================ launch
extern "C" void kernel_launch(void* const* d_in, const int* in_sizes, int n_in,
                              void* d_out, int out_size, void* d_ws, size_t ws_size,
                              hipStream_t stream) {
    const float* x  = (const float*)d_in[0];
    const int*   ei = (const int*)d_in[1];
    // d_in[2] = batch (derived analytically, unused)
    const float* W  = (const float*)d_in[3];
    const float* bp = (const float*)d_in[4];
    float* out = (float*)d_out;

    int esel  = (out_size - BB * KK * DD - BB * KK - 1) / 2;  // kept-edge count
    int off_e = BB * KK * DD;
    int off_b = off_e + 2 * esel;

    float* ws     = (float*)d_ws;
    float* h      = ws;                  // NN floats
    float* acc    = ws + NN;             // NN floats
    int*   deg    = (int*)(ws + 2 * NN); // NN ints
    int*   lnewid = deg + NN;            // NN ints (global new ids or -1)
    unsigned* packed = (unsigned*)(lnewid + NN);  // EE uints
    int*   counts = (int*)(packed + EE); // 256 ints

    k1_init_h<<<256, 256, 0, stream>>>(x, W, h, deg, acc, out, out_size);
    k2_deg<<<256, 256, 0, stream>>>(ei, deg);
    k3_scatter<<<256, 256, 0, stream>>>(ei, deg, h, acc);
    k4_rank<<<256, 256, 0, stream>>>(x, deg, h, acc, bp, lnewid, out, off_b);
    k5_resolve<<<256, 256, 0, stream>>>(ei, lnewid, packed, counts);
    k6_edges<<<256, 256, 0, stream>>>(packed, counts, out, esel, off_e);
}